// Round 1
// baseline (684.674 us; speedup 1.0000x reference)
//
#include <hip/hip_runtime.h>

#define NNODE 50000
#define NEDGE 800000

// ---------------- degree / norm ----------------

__global__ void k_deg_init(float* __restrict__ deg) {
    int i = blockIdx.x * blockDim.x + threadIdx.x;
    if (i < NNODE) deg[i] = 1.0f;   // self loop
}

__global__ void k_deg_count(const int* __restrict__ dst, float* __restrict__ deg) {
    int i = blockIdx.x * blockDim.x + threadIdx.x;
    if (i < NEDGE) atomicAdd(&deg[dst[i]], 1.0f);
}

__global__ void k_dinv(float* __restrict__ deg) {
    int i = blockIdx.x * blockDim.x + threadIdx.x;
    if (i < NNODE) deg[i] = rsqrtf(deg[i]);   // deg >= 1 always (self loop)
}

// ---------------- GEMM + prescale by dinv[row] ----------------
// XWs[row][col] = (X[row] . W[:,col]) * dinv[row]; agg initialized to XWs
// (self-loop message, since self-loop contributes dinv[i]*XWs[i] before the
// final dinv[i] multiply in finalize).

template<int FIN, int FOUT>
__launch_bounds__(256)
__global__ void k_gemm_prescale(const float* __restrict__ X, const float* __restrict__ W,
                                const float* __restrict__ dinv,
                                float* __restrict__ XWs, float* __restrict__ agg) {
    __shared__ float Ws[FIN * FOUT];
    for (int i = threadIdx.x; i < FIN * FOUT; i += 256) Ws[i] = W[i];
    __syncthreads();

    int idx = blockIdx.x * 256 + threadIdx.x;
    if (idx >= NNODE * FOUT) return;
    int row = idx / FOUT;
    int col = idx - row * FOUT;

    const float* xr = X + (long long)row * FIN;
    float acc = 0.0f;
#pragma unroll
    for (int k = 0; k < FIN; ++k)
        acc = fmaf(xr[k], Ws[k * FOUT + col], acc);

    float v = acc * dinv[row];
    XWs[idx] = v;
    agg[idx] = v;
}

// ---------------- edge scatter (atomic) ----------------
// agg[dst][f] += XWs[src][f]

template<int F>
__launch_bounds__(256)
__global__ void k_scatter(const int* __restrict__ src, const int* __restrict__ dst,
                          const float* __restrict__ XWs, float* __restrict__ agg) {
    int idx = blockIdx.x * 256 + threadIdx.x;
    if (idx >= NEDGE * F) return;
    int e = idx / F;
    int f = idx - e * F;
    int s = src[e];
    int d = dst[e];
    atomicAdd(&agg[d * F + f], XWs[s * F + f]);
}

// ---------------- finalize: out = act(dinv[row]*agg + b) ----------------

template<int F, bool RELU>
__launch_bounds__(256)
__global__ void k_finalize(const float* __restrict__ agg, const float* __restrict__ dinv,
                           const float* __restrict__ b, float* __restrict__ out) {
    int idx = blockIdx.x * 256 + threadIdx.x;
    if (idx >= NNODE * F) return;
    int row = idx / F;
    int f = idx - row * F;
    float v = fmaf(agg[idx], dinv[row], b[f]);
    out[idx] = RELU ? fmaxf(v, 0.0f) : v;
}

extern "C" void kernel_launch(void* const* d_in, const int* in_sizes, int n_in,
                              void* d_out, int out_size, void* d_ws, size_t ws_size,
                              hipStream_t stream) {
    const float* x  = (const float*)d_in[0];
    const int*   ei = (const int*)d_in[1];     // [2, E] int (harness converts int64->int32)
    const float* W1 = (const float*)d_in[2];
    const float* b1 = (const float*)d_in[3];
    const float* W2 = (const float*)d_in[4];
    const float* b2 = (const float*)d_in[5];
    const float* W3 = (const float*)d_in[6];
    const float* b3 = (const float*)d_in[7];
    float* out = (float*)d_out;

    const int* src = ei;
    const int* dst = ei + NEDGE;

    // workspace layout (floats)
    float* ws   = (float*)d_ws;
    float* dinv = ws;                         // N  (deg then dinv in-place)
    float* XWs  = ws + 50176;                 // N*64
    float* agg  = XWs + NNODE * 64;           // N*64
    float* H1   = agg + NNODE * 64;           // N*64
    float* H2   = H1 + NNODE * 64;            // N*64

    const int B = 256;
    const int gN   = (NNODE + B - 1) / B;
    const int gE   = (NEDGE + B - 1) / B;
    const int g64  = (NNODE * 64 + B - 1) / B;
    const int g40  = (NNODE * 40 + B - 1) / B;
    const int gs64 = (NEDGE * 64 + B - 1) / B;
    const int gs40 = (NEDGE * 40 + B - 1) / B;

    // normalization
    k_deg_init<<<gN, B, 0, stream>>>(dinv);
    k_deg_count<<<gE, B, 0, stream>>>(dst, dinv);
    k_dinv<<<gN, B, 0, stream>>>(dinv);

    // layer 1: 128 -> 64, relu
    k_gemm_prescale<128, 64><<<g64, B, 0, stream>>>(x, W1, dinv, XWs, agg);
    k_scatter<64><<<gs64, B, 0, stream>>>(src, dst, XWs, agg);
    k_finalize<64, true><<<g64, B, 0, stream>>>(agg, dinv, b1, H1);

    // layer 2: 64 -> 64, relu
    k_gemm_prescale<64, 64><<<g64, B, 0, stream>>>(H1, W2, dinv, XWs, agg);
    k_scatter<64><<<gs64, B, 0, stream>>>(src, dst, XWs, agg);
    k_finalize<64, true><<<g64, B, 0, stream>>>(agg, dinv, b2, H2);

    // layer 3: 64 -> 40, no act
    k_gemm_prescale<64, 40><<<g40, B, 0, stream>>>(H2, W3, dinv, XWs, agg);
    k_scatter<40><<<gs40, B, 0, stream>>>(src, dst, XWs, agg);
    k_finalize<40, false><<<g40, B, 0, stream>>>(agg, dinv, b3, out);
}

// Round 3
// 389.362 us; speedup vs baseline: 1.7585x; 1.7585x over previous
//
#include <hip/hip_runtime.h>

#define NNODE 50000
#define NEDGE 800000
#define NB1   196        // ceil(50000/256)

// ---------------- CSR build: count, scan, fill ----------------

__global__ void k_zero(int* __restrict__ cnt) {
    int i = blockIdx.x * 256 + threadIdx.x;
    if (i < NNODE) cnt[i] = 0;
}

__global__ void k_count(const int* __restrict__ dst, int* __restrict__ cnt) {
    int i = blockIdx.x * 256 + threadIdx.x;
    if (i < NEDGE) atomicAdd(&cnt[dst[i]], 1);
}

// inclusive block scan of cnt -> incl, block totals -> bsum
__global__ void k_scan1(const int* __restrict__ cnt, int* __restrict__ incl, int* __restrict__ bsum) {
    __shared__ int s[256];
    int i = blockIdx.x * 256 + threadIdx.x;
    int v = (i < NNODE) ? cnt[i] : 0;
    s[threadIdx.x] = v;
    __syncthreads();
#pragma unroll
    for (int off = 1; off < 256; off <<= 1) {
        int t = (threadIdx.x >= off) ? s[threadIdx.x - off] : 0;
        __syncthreads();
        s[threadIdx.x] += t;
        __syncthreads();
    }
    if (i < NNODE) incl[i] = s[threadIdx.x];
    if (threadIdx.x == 255) bsum[blockIdx.x] = s[255];
}

// single-block inclusive scan of bsum (NB1 <= 256)
__global__ void k_scan2(int* __restrict__ bsum) {
    __shared__ int s[256];
    int v = (threadIdx.x < NB1) ? bsum[threadIdx.x] : 0;
    s[threadIdx.x] = v;
    __syncthreads();
#pragma unroll
    for (int off = 1; off < 256; off <<= 1) {
        int t = (threadIdx.x >= off) ? s[threadIdx.x - off] : 0;
        __syncthreads();
        s[threadIdx.x] += t;
        __syncthreads();
    }
    if (threadIdx.x < NB1) bsum[threadIdx.x] = s[threadIdx.x];
}

// rowstart[i+1] = inclusive(i); cursor[i] = exclusive(i); dinv[i] = rsqrt(deg)
__global__ void k_scan3(const int* __restrict__ incl, const int* __restrict__ bsum,
                        const int* __restrict__ cnt, int* __restrict__ rowstart,
                        int* __restrict__ cursor, float* __restrict__ dinv) {
    int i = blockIdx.x * 256 + threadIdx.x;
    if (i >= NNODE) return;
    int boff = (blockIdx.x == 0) ? 0 : bsum[blockIdx.x - 1];
    int inc = incl[i] + boff;
    rowstart[i + 1] = inc;
    cursor[i] = inc - cnt[i];
    dinv[i] = rsqrtf((float)cnt[i] + 1.0f);   // +1 self loop
    if (i == 0) rowstart[0] = 0;
}

__global__ void k_fill(const int* __restrict__ src, const int* __restrict__ dst,
                       int* __restrict__ cursor, int* __restrict__ csr_src) {
    int e = blockIdx.x * 256 + threadIdx.x;
    if (e >= NEDGE) return;
    int d = dst[e];
    int pos = atomicAdd(&cursor[d], 1);
    csr_src[pos] = src[e];
}

// ---------------- GEMM + prescale by dinv[row] ----------------
// XWs[row][col] = (X[row] . W[:,col]) * dinv[row]

template<int FIN, int FOUT>
__launch_bounds__(256)
__global__ void k_gemm_prescale(const float* __restrict__ X, const float* __restrict__ W,
                                const float* __restrict__ dinv, float* __restrict__ XWs) {
    __shared__ float Ws[FIN * FOUT];
    for (int i = threadIdx.x; i < FIN * FOUT; i += 256) Ws[i] = W[i];
    __syncthreads();

    int idx = blockIdx.x * 256 + threadIdx.x;
    if (idx >= NNODE * FOUT) return;
    int row = idx / FOUT;
    int col = idx - row * FOUT;

    const float4* xr4 = (const float4*)(X + (long long)row * FIN);
    float acc = 0.0f;
#pragma unroll
    for (int k4 = 0; k4 < FIN / 4; ++k4) {
        float4 xv = xr4[k4];
        acc = fmaf(xv.x, Ws[(k4 * 4 + 0) * FOUT + col], acc);
        acc = fmaf(xv.y, Ws[(k4 * 4 + 1) * FOUT + col], acc);
        acc = fmaf(xv.z, Ws[(k4 * 4 + 2) * FOUT + col], acc);
        acc = fmaf(xv.w, Ws[(k4 * 4 + 3) * FOUT + col], acc);
    }
    XWs[idx] = acc * dinv[row];
}

// ---------------- CSR aggregate + finalize ----------------
// out[d][f] = act(dinv[d] * (XWs[d][f] + sum_{e in row d} XWs[src_e][f]) + b[f])
// one wave per destination node; lane = feature

template<int F, bool RELU>
__launch_bounds__(256)
__global__ void k_aggregate(const float* __restrict__ XWs, const int* __restrict__ rowstart,
                            const int* __restrict__ csr_src, const float* __restrict__ dinv,
                            const float* __restrict__ b, float* __restrict__ out) {
    int wid  = threadIdx.x >> 6;
    int lane = threadIdx.x & 63;
    int d = blockIdx.x * 4 + wid;
    if (d >= NNODE) return;

    int beg = rowstart[d];
    int end = rowstart[d + 1];

    float acc = (lane < F) ? XWs[(long long)d * F + lane] : 0.0f;  // self loop

    for (int base = beg; base < end; base += 64) {
        int idx = base + lane;
        int sv = (idx < end) ? csr_src[idx] : 0;   // coalesced edge-list load
        int nv = min(64, end - base);
        for (int j = 0; j < nv; ++j) {
            int s = __shfl(sv, j);                 // broadcast src id
            if (lane < F) acc += XWs[(long long)s * F + lane];
        }
    }

    if (lane < F) {
        float v = fmaf(acc, dinv[d], b[lane]);
        out[(long long)d * F + lane] = RELU ? fmaxf(v, 0.0f) : v;
    }
}

extern "C" void kernel_launch(void* const* d_in, const int* in_sizes, int n_in,
                              void* d_out, int out_size, void* d_ws, size_t ws_size,
                              hipStream_t stream) {
    const float* x  = (const float*)d_in[0];
    const int*   ei = (const int*)d_in[1];
    const float* W1 = (const float*)d_in[2];
    const float* b1 = (const float*)d_in[3];
    const float* W2 = (const float*)d_in[4];
    const float* b2 = (const float*)d_in[5];
    const float* W3 = (const float*)d_in[6];
    const float* b3 = (const float*)d_in[7];
    float* out = (float*)d_out;

    const int* src = ei;
    const int* dst = ei + NEDGE;

    // workspace layout
    char* p = (char*)d_ws;
    auto alloc = [&](size_t bytes) { char* r = p; p += (bytes + 255) & ~size_t(255); return r; };
    int*   cnt      = (int*)  alloc(NNODE * 4);
    int*   incl     = (int*)  alloc(NNODE * 4);
    int*   bsum     = (int*)  alloc(256 * 4);
    int*   rowstart = (int*)  alloc((NNODE + 1) * 4);
    int*   cursor   = (int*)  alloc(NNODE * 4);
    int*   csr_src  = (int*)  alloc(NEDGE * 4);
    float* dinv     = (float*)alloc(NNODE * 4);
    float* XWs      = (float*)alloc((size_t)NNODE * 64 * 4);
    float* H1       = (float*)alloc((size_t)NNODE * 64 * 4);
    float* H2       = (float*)alloc((size_t)NNODE * 64 * 4);

    const int B = 256;
    const int gN   = NB1;                        // 196
    const int gE   = (NEDGE + B - 1) / B;        // 3125
    const int g64  = (NNODE * 64 + B - 1) / B;
    const int g40  = (NNODE * 40 + B - 1) / B;
    const int gAgg = (NNODE + 3) / 4;            // 12500 (4 waves/block, 1 node/wave)

    // CSR build + norm
    k_zero <<<gN, B, 0, stream>>>(cnt);
    k_count<<<gE, B, 0, stream>>>(dst, cnt);
    k_scan1<<<gN, B, 0, stream>>>(cnt, incl, bsum);
    k_scan2<<<1,  B, 0, stream>>>(bsum);
    k_scan3<<<gN, B, 0, stream>>>(incl, bsum, cnt, rowstart, cursor, dinv);
    k_fill <<<gE, B, 0, stream>>>(src, dst, cursor, csr_src);

    // layer 1: 128 -> 64, relu
    k_gemm_prescale<128, 64><<<g64, B, 0, stream>>>(x, W1, dinv, XWs);
    k_aggregate<64, true><<<gAgg, B, 0, stream>>>(XWs, rowstart, csr_src, dinv, b1, H1);

    // layer 2: 64 -> 64, relu
    k_gemm_prescale<64, 64><<<g64, B, 0, stream>>>(H1, W2, dinv, XWs);
    k_aggregate<64, true><<<gAgg, B, 0, stream>>>(XWs, rowstart, csr_src, dinv, b2, H2);

    // layer 3: 64 -> 40, no act
    k_gemm_prescale<64, 40><<<g40, B, 0, stream>>>(H2, W3, dinv, XWs);
    k_aggregate<40, false><<<gAgg, B, 0, stream>>>(XWs, rowstart, csr_src, dinv, b3, out);
}

// Round 4
// 320.449 us; speedup vs baseline: 2.1366x; 1.2150x over previous
//
#include <hip/hip_runtime.h>

#define NNODE 50000
#define NEDGE 800000
#define NB1   196        // ceil(50000/256)

// ---------------- CSR build: count, scan, fill ----------------

__global__ void k_zero(int* __restrict__ cnt) {
    int i = blockIdx.x * 256 + threadIdx.x;
    if (i < NNODE) cnt[i] = 0;
}

__global__ void k_count(const int* __restrict__ dst, int* __restrict__ cnt) {
    int i = blockIdx.x * 256 + threadIdx.x;
    if (i < NEDGE) atomicAdd(&cnt[dst[i]], 1);
}

__global__ void k_scan1(const int* __restrict__ cnt, int* __restrict__ incl, int* __restrict__ bsum) {
    __shared__ int s[256];
    int i = blockIdx.x * 256 + threadIdx.x;
    int v = (i < NNODE) ? cnt[i] : 0;
    s[threadIdx.x] = v;
    __syncthreads();
#pragma unroll
    for (int off = 1; off < 256; off <<= 1) {
        int t = (threadIdx.x >= off) ? s[threadIdx.x - off] : 0;
        __syncthreads();
        s[threadIdx.x] += t;
        __syncthreads();
    }
    if (i < NNODE) incl[i] = s[threadIdx.x];
    if (threadIdx.x == 255) bsum[blockIdx.x] = s[255];
}

__global__ void k_scan2(int* __restrict__ bsum) {
    __shared__ int s[256];
    int v = (threadIdx.x < NB1) ? bsum[threadIdx.x] : 0;
    s[threadIdx.x] = v;
    __syncthreads();
#pragma unroll
    for (int off = 1; off < 256; off <<= 1) {
        int t = (threadIdx.x >= off) ? s[threadIdx.x - off] : 0;
        __syncthreads();
        s[threadIdx.x] += t;
        __syncthreads();
    }
    if (threadIdx.x < NB1) bsum[threadIdx.x] = s[threadIdx.x];
}

__global__ void k_scan3(const int* __restrict__ incl, const int* __restrict__ bsum,
                        const int* __restrict__ cnt, int* __restrict__ rowstart,
                        int* __restrict__ cursor, float* __restrict__ dinv) {
    int i = blockIdx.x * 256 + threadIdx.x;
    if (i >= NNODE) return;
    int boff = (blockIdx.x == 0) ? 0 : bsum[blockIdx.x - 1];
    int inc = incl[i] + boff;
    rowstart[i + 1] = inc;
    cursor[i] = inc - cnt[i];
    dinv[i] = rsqrtf((float)cnt[i] + 1.0f);   // +1 self loop
    if (i == 0) rowstart[0] = 0;
}

__global__ void k_fill(const int* __restrict__ src, const int* __restrict__ dst,
                       int* __restrict__ cursor, int* __restrict__ csr_src) {
    int e = blockIdx.x * 256 + threadIdx.x;
    if (e >= NEDGE) return;
    int d = dst[e];
    int pos = atomicAdd(&cursor[d], 1);
    csr_src[pos] = src[e];
}

// ---------------- GEMM + prescale by dinv[row] ----------------
// Register-tiled: wave = 64 cols (lane=col), 4 rows/wave, 16 rows/block.
// Per k: 1 ds_read (W) feeds 4 independent FMAs; x loaded as float4.
// 50000 = 16 * 3125 exactly -> no row bounds checks.

template<int FIN, int FOUT>
__launch_bounds__(256)
__global__ void k_gemm_prescale(const float* __restrict__ X, const float* __restrict__ W,
                                const float* __restrict__ dinv, float* __restrict__ XWs) {
    __shared__ float Ws[FIN * FOUT + 64];   // +64 pad: lanes >= FOUT read garbage harmlessly
    for (int i = threadIdx.x; i < FIN * FOUT; i += 256) Ws[i] = W[i];
    __syncthreads();

    int wid  = threadIdx.x >> 6;
    int lane = threadIdx.x & 63;
    int row0 = blockIdx.x * 16 + wid * 4;

    const float4* x0 = (const float4*)(X + (size_t)(row0 + 0) * FIN);
    const float4* x1 = (const float4*)(X + (size_t)(row0 + 1) * FIN);
    const float4* x2 = (const float4*)(X + (size_t)(row0 + 2) * FIN);
    const float4* x3 = (const float4*)(X + (size_t)(row0 + 3) * FIN);

    float acc0 = 0.f, acc1 = 0.f, acc2 = 0.f, acc3 = 0.f;
#pragma unroll
    for (int k4 = 0; k4 < FIN / 4; ++k4) {
        float4 a = x0[k4], b = x1[k4], c = x2[k4], d = x3[k4];
#pragma unroll
        for (int j = 0; j < 4; ++j) {
            float w = Ws[(k4 * 4 + j) * FOUT + lane];
            float av = (j == 0) ? a.x : (j == 1) ? a.y : (j == 2) ? a.z : a.w;
            float bv = (j == 0) ? b.x : (j == 1) ? b.y : (j == 2) ? b.z : b.w;
            float cv = (j == 0) ? c.x : (j == 1) ? c.y : (j == 2) ? c.z : c.w;
            float dv = (j == 0) ? d.x : (j == 1) ? d.y : (j == 2) ? d.z : d.w;
            acc0 = fmaf(av, w, acc0);
            acc1 = fmaf(bv, w, acc1);
            acc2 = fmaf(cv, w, acc2);
            acc3 = fmaf(dv, w, acc3);
        }
    }

    if (lane < FOUT) {
        XWs[(size_t)(row0 + 0) * FOUT + lane] = acc0 * dinv[row0 + 0];
        XWs[(size_t)(row0 + 1) * FOUT + lane] = acc1 * dinv[row0 + 1];
        XWs[(size_t)(row0 + 2) * FOUT + lane] = acc2 * dinv[row0 + 2];
        XWs[(size_t)(row0 + 3) * FOUT + lane] = acc3 * dinv[row0 + 3];
    }
}

// ---------------- CSR aggregate + finalize ----------------
// out[d][f] = act(dinv[d] * (XWs[d][f] + sum_{e in row d} XWs[src_e][f]) + b[f])
// one wave per destination node; lane = feature; gather unrolled x4 for MLP.

template<int F, bool RELU>
__launch_bounds__(256)
__global__ void k_aggregate(const float* __restrict__ XWs, const int* __restrict__ rowstart,
                            const int* __restrict__ csr_src, const float* __restrict__ dinv,
                            const float* __restrict__ b, float* __restrict__ out) {
    int wid  = threadIdx.x >> 6;
    int lane = threadIdx.x & 63;
    int d = blockIdx.x * 4 + wid;
    if (d >= NNODE) return;

    int beg = rowstart[d];
    int end = rowstart[d + 1];

    float acc = (lane < F) ? XWs[(size_t)d * F + lane] : 0.0f;  // self loop

    for (int base = beg; base < end; base += 64) {
        int idx = base + lane;
        int sv = (idx < end) ? csr_src[idx] : 0;   // coalesced edge-list load
        int nv = min(64, end - base);
        int j = 0;
        for (; j + 4 <= nv; j += 4) {
            int s0 = __shfl(sv, j + 0);
            int s1 = __shfl(sv, j + 1);
            int s2 = __shfl(sv, j + 2);
            int s3 = __shfl(sv, j + 3);
            float v0 = XWs[(size_t)s0 * F + lane];  // 4 independent loads in flight
            float v1 = XWs[(size_t)s1 * F + lane];
            float v2 = XWs[(size_t)s2 * F + lane];
            float v3 = XWs[(size_t)s3 * F + lane];
            acc += v0; acc += v1; acc += v2; acc += v3;
        }
        for (; j < nv; ++j) {
            int s = __shfl(sv, j);
            acc += XWs[(size_t)s * F + lane];
        }
    }

    if (lane < F) {
        float v = fmaf(acc, dinv[d], b[lane]);
        out[(size_t)d * F + lane] = RELU ? fmaxf(v, 0.0f) : v;
    }
}

extern "C" void kernel_launch(void* const* d_in, const int* in_sizes, int n_in,
                              void* d_out, int out_size, void* d_ws, size_t ws_size,
                              hipStream_t stream) {
    const float* x  = (const float*)d_in[0];
    const int*   ei = (const int*)d_in[1];
    const float* W1 = (const float*)d_in[2];
    const float* b1 = (const float*)d_in[3];
    const float* W2 = (const float*)d_in[4];
    const float* b2 = (const float*)d_in[5];
    const float* W3 = (const float*)d_in[6];
    const float* b3 = (const float*)d_in[7];
    float* out = (float*)d_out;

    const int* src = ei;
    const int* dst = ei + NEDGE;

    char* p = (char*)d_ws;
    auto alloc = [&](size_t bytes) { char* r = p; p += (bytes + 255) & ~size_t(255); return r; };
    int*   cnt      = (int*)  alloc(NNODE * 4);
    int*   incl     = (int*)  alloc(NNODE * 4);
    int*   bsum     = (int*)  alloc(256 * 4);
    int*   rowstart = (int*)  alloc((NNODE + 1) * 4);
    int*   cursor   = (int*)  alloc(NNODE * 4);
    int*   csr_src  = (int*)  alloc(NEDGE * 4);
    float* dinv     = (float*)alloc(NNODE * 4);
    float* XWs      = (float*)alloc((size_t)NNODE * 64 * 4 + 256);  // +pad for F=40 OOB-read slack
    float* H1       = (float*)alloc((size_t)NNODE * 64 * 4);
    float* H2       = (float*)alloc((size_t)NNODE * 64 * 4);

    const int B = 256;
    const int gN    = NB1;                        // 196
    const int gE    = (NEDGE + B - 1) / B;        // 3125
    const int gGemm = NNODE / 16;                 // 3125 (16 rows/block, exact)
    const int gAgg  = (NNODE + 3) / 4;            // 12500

    // CSR build + norm
    k_zero <<<gN, B, 0, stream>>>(cnt);
    k_count<<<gE, B, 0, stream>>>(dst, cnt);
    k_scan1<<<gN, B, 0, stream>>>(cnt, incl, bsum);
    k_scan2<<<1,  B, 0, stream>>>(bsum);
    k_scan3<<<gN, B, 0, stream>>>(incl, bsum, cnt, rowstart, cursor, dinv);
    k_fill <<<gE, B, 0, stream>>>(src, dst, cursor, csr_src);

    // layer 1: 128 -> 64, relu
    k_gemm_prescale<128, 64><<<gGemm, B, 0, stream>>>(x, W1, dinv, XWs);
    k_aggregate<64, true><<<gAgg, B, 0, stream>>>(XWs, rowstart, csr_src, dinv, b1, H1);

    // layer 2: 64 -> 64, relu
    k_gemm_prescale<64, 64><<<gGemm, B, 0, stream>>>(H1, W2, dinv, XWs);
    k_aggregate<64, true><<<gAgg, B, 0, stream>>>(XWs, rowstart, csr_src, dinv, b2, H2);

    // layer 3: 64 -> 40, no act
    k_gemm_prescale<64, 40><<<gGemm, B, 0, stream>>>(H2, W3, dinv, XWs);
    k_aggregate<40, false><<<gAgg, B, 0, stream>>>(XWs, rowstart, csr_src, dinv, b3, out);
}